// Round 6
// baseline (241.322 us; speedup 1.0000x reference)
//
#include <hip/hip_runtime.h>

// GCNFast: out[b,s,t,d] = relu( sum_j relu(AA[i%64,j%64]*GCW[i,j]) * X[j,b,d] + GCB[i,d] )
// Sparsity: AA (64x64, ~50% dense) -> per row-group s, support supp(s).
// K reordered kk=c*64+t; A' compact [s*64+tt][ci*64+t], XT' [b*128+d][c*64+t].
// Round-6: PAIRED-UNION gemm. Empirical law rounds 1-5: gemm dur ~= staged_bytes
//   / ~10.8 TB/s (occupancy & ratio changes were null). So cut staged bytes:
//   one block computes s0=2p AND s1=2p+1 (BM=128), staging X once per
//   c in supp(s0) U supp(s1) (~48 tiles vs 64). A halves predicated: absent
//   half still issues its load (vmcnt stays exact) but skips frag-reads+MFMA
//   (wave-uniform: waves 0-3 own s0, 4-7 own s1). Union list ascending-c ->
//   summation order identical to r4/r5. 8 waves, acc[4][4], dbuf 96KB,
//   vmcnt(6), grid 32 pairs x 8 n-panels.
// Fallback to fused single-kernel path if ws too small.

#define NC 64
#define NS 64
#define NT 64
#define DH 128
#define BATCH 16
#define MDIM 4096
#define KDIM 4096
#define KPAD 4096
#define TM 128
#define TK 64
#define GBM 128
#define GBN 256
#define GBK 64

typedef __attribute__((ext_vector_type(8))) short short8;
typedef __attribute__((ext_vector_type(4))) short short4v;
typedef __attribute__((ext_vector_type(4))) float floatx4;

__device__ __forceinline__ unsigned short f2bf(float f) {
    union { float f; unsigned int i; } v; v.f = f;
    return (unsigned short)((v.i + 0x7fffu + ((v.i >> 16) & 1u)) >> 16);
}
__device__ __forceinline__ void async16(const void* g, void* l) {
    __builtin_amdgcn_global_load_lds(
        (const __attribute__((address_space(1))) void*)g,
        (__attribute__((address_space(3))) void*)l, 16, 0, 0);
}

// ---- fused prep ----
// blocks [0,1024): 4 rows of A' each (same s): A'[s*64+tt][ci*64+t] =
//   relu(GCW[tt*64+s][t*64+c_i]) via direct global gather. Block with tt0==0
//   and even s also builds the pair union list cpair[p][.]:
//   entry = c | f0<<6 | f1<<7 | ci0<<8 | ci1<<14, and ntp[p]=|union|.
// blocks [1024,2048): XT'[b*128+d][c*64+t] = bf16(h[b,c,t,d]) via LDS transpose.
__global__ __launch_bounds__(256)
void prep(const float* __restrict__ aam, const float* __restrict__ gcw,
          const float* __restrict__ hmat,
          unsigned short* __restrict__ Abf, unsigned short* __restrict__ XT,
          int* __restrict__ cpair, int* __restrict__ ntp)
{
    const int tid = threadIdx.x;
    if ((int)blockIdx.x < 1024) {
        const int blk = blockIdx.x;
        const int s   = blk >> 4;          // 16 blocks per s
        const int tt0 = (blk & 15) * 4;    // 4 rows per block
        __shared__ unsigned short scidx[64];
        __shared__ int sns;
        if (tid < 64) {
            float v = aam[(size_t)s * KDIM + tid];
            unsigned long long m = __ballot(v != 0.f);
            int rank = __popcll(m & ((1ull << tid) - 1ull));
            if (v != 0.f) scidx[rank] = (unsigned short)tid;
            if (tid == 0) sns = (int)__popcll(m);
            if (tt0 == 0 && (s & 1) == 0) {
                float v1 = aam[(size_t)(s + 1) * KDIM + tid];
                unsigned long long m1 = __ballot(v1 != 0.f);
                unsigned long long mu = m | m1;
                if ((mu >> tid) & 1ull) {
                    int ur  = __popcll(mu & ((1ull << tid) - 1ull));
                    int ci0 = __popcll(m  & ((1ull << tid) - 1ull));
                    int ci1 = __popcll(m1 & ((1ull << tid) - 1ull));
                    int f0  = (int)((m  >> tid) & 1ull);
                    int f1  = (int)((m1 >> tid) & 1ull);
                    cpair[(s >> 1) * 64 + ur] =
                        tid | (f0 << 6) | (f1 << 7) | (ci0 << 8) | (ci1 << 14);
                }
                if (tid == 0) ntp[s >> 1] = (int)__popcll(mu);
            }
        }
        __syncthreads();
        const int ke = sns * 64;   // multiple of 64
#pragma unroll
        for (int rr = 0; rr < 4; ++rr) {
            const int tt = tt0 + rr;
            const int i  = tt * 64 + s;
            const int r  = s * 64 + tt;
            const float* gr = gcw + (size_t)i * KDIM;
            for (int kk0 = tid * 8; kk0 < ke; kk0 += 2048) {
                const int c  = (int)scidx[kk0 >> 6];
                const int t0 = kk0 & 63;
                short8 p;
#pragma unroll
                for (int e = 0; e < 8; ++e) {
                    float v = gr[(t0 + e) * 64 + c];
                    v = v > 0.f ? v : 0.f;
                    p[e] = (short)f2bf(v);
                }
                *(short8*)(Abf + (size_t)r * KPAD + kk0) = p;
            }
        }
    } else {
        const int blk = blockIdx.x - 1024;
        const int b = blk >> 6;
        const int c = blk & 63;
        __shared__ unsigned short sx[64][136];
        const float* hp = hmat + (((size_t)b * NC + c) * NT) * DH;
#pragma unroll
        for (int u = 0; u < 8; ++u) {
            const int idx = u * 1024 + tid * 4;   // float idx in [64t][128d]
            const int t = idx >> 7;
            const int d = idx & 127;
            floatx4 v = *(const floatx4*)(hp + idx);
            short4v p;
#pragma unroll
            for (int e = 0; e < 4; ++e) p[e] = (short)f2bf(v[e]);
            *(short4v*)&sx[t][d] = p;
        }
        __syncthreads();
        const int d  = tid >> 1;
        const int th = (tid & 1) * 32;
        unsigned short* dst = XT + ((size_t)(b * DH + d)) * KPAD + c * 64 + th;
#pragma unroll
        for (int u2 = 0; u2 < 4; ++u2) {
            short8 p;
#pragma unroll
            for (int e = 0; e < 8; ++e)
                p[e] = (short)sx[th + u2 * 8 + e][d];
            *(short8*)(dst + u2 * 8) = p;
        }
    }
}

// ---- GEMM: pair tile C[128, 256], K over union c-tiles, predicated halves ----
__global__ __launch_bounds__(512, 2)
void gemm(const unsigned short* __restrict__ Abf,
          const unsigned short* __restrict__ XT,
          const int* __restrict__ cpair,
          const int* __restrict__ ntp,
          const float* __restrict__ gcb,
          float* __restrict__ out)
{
    __shared__ short lds[2][(GBM + GBN) * GBK];   // 2 x 48 KB = 96 KB

    const int tid = threadIdx.x;
    const int bid = blockIdx.x;
    const int np = bid & 7;        // n-panel (256 cols = 2 batches); XCD-affine
    const int p  = bid >> 3;       // pair 0..31  (s0=2p, s1=2p+1)
    const int n0 = np * GBN;

    const int lane = tid & 63;
    const int w    = tid >> 6;        // 0..7
    const int wm   = (w >> 2) * 64;   // waves 0-3 -> s0 rows, 4-7 -> s1 rows
    const int wn   = (w & 3) * 64;
    const int l15  = lane & 15;
    const int q    = lane >> 4;
    const int srow = lane >> 3;
    const int swz  = ((lane & 7) ^ srow) << 3;   // swizzled k-chunk (elements)
    const int half = wm >> 6;                    // 0 or 1

    const int nt = ntp[p];
    const int ep = cpair[p * 64 + lane];   // lane ur holds union entry ur

    const unsigned short* Abp = Abf + (size_t)(p * 128) * KPAD + swz;  // pair rows contiguous
    const unsigned short* Xb  = XT  + (size_t)n0 * KPAD + swz;

    floatx4 acc[4][4];
#pragma unroll
    for (int mi = 0; mi < 4; ++mi)
#pragma unroll
        for (int ni = 0; ni < 4; ++ni)
            acc[mi][ni] = (floatx4){0.f, 0.f, 0.f, 0.f};

    // 6 loads per wave per tile, ALWAYS issued (vmcnt exact): A0, A1, 4x X
    auto stage = [&](int t, int b) {
        short* dst = lds[b];
        const int e   = __shfl(ep, t);
        const int kx  = (e & 63) << 6;
        const int ka0 = ((e >> 8) & 63) << 6;
        const int ka1 = ((e >> 14) & 63) << 6;
        async16(Abp + (size_t)(w * 8 + srow) * KPAD + ka0,      dst + (w * 8) * GBK);
        async16(Abp + (size_t)(64 + w * 8 + srow) * KPAD + ka1, dst + (64 + w * 8) * GBK);
#pragma unroll
        for (int g = 0; g < 4; ++g) {
            const int rr = g * 64 + w * 8;
            async16(Xb + (size_t)(rr + srow) * KPAD + kx, dst + (GBM + rr) * GBK);
        }
    };

    auto compute = [&](int b) {
        const short* sA = lds[b];
        const short* sX = lds[b] + GBM * GBK;
#pragma unroll
        for (int h2 = 0; h2 < 2; ++h2) {
            const int co = ((h2 * 4 + q) ^ (l15 & 7)) << 3;
            short8 af[4], xf[4];
#pragma unroll
            for (int mi = 0; mi < 4; ++mi)
                af[mi] = *(const short8*)&sA[(wm + mi * 16 + l15) * GBK + co];
#pragma unroll
            for (int ni = 0; ni < 4; ++ni)
                xf[ni] = *(const short8*)&sX[(wn + ni * 16 + l15) * GBK + co];
            __builtin_amdgcn_s_setprio(1);
#pragma unroll
            for (int mi = 0; mi < 4; ++mi)
#pragma unroll
                for (int ni = 0; ni < 4; ++ni)
                    acc[mi][ni] = __builtin_amdgcn_mfma_f32_16x16x32_bf16(
                        af[mi], xf[ni], acc[mi][ni], 0, 0, 0);
            __builtin_amdgcn_s_setprio(0);
        }
    };

    if (nt > 0) stage(0, 0);
    if (nt > 1) stage(1, 1);
    for (int t = 0; t < nt - 1; ++t) {
        // t's 6 loads retired; (t+1)'s 6 stay in flight
        asm volatile("s_waitcnt vmcnt(6)" ::: "memory");
        __builtin_amdgcn_s_barrier();
        const int f = (__shfl(ep, t) >> (6 + half)) & 1;   // my half present?
        if (f) compute(t & 1);
        __builtin_amdgcn_s_barrier();
        if (t + 2 < nt) stage(t + 2, t & 1);
    }
    if (nt > 0) {
        asm volatile("s_waitcnt vmcnt(0)" ::: "memory");
        __builtin_amdgcn_s_barrier();
        const int f = (__shfl(ep, nt - 1) >> (6 + half)) & 1;
        if (f) compute((nt - 1) & 1);
    }

    // epilogue: local row (within half) = mi*16+q*4+r = tt; s = 2p+half
    const int s = 2 * p + half;
#pragma unroll
    for (int mi = 0; mi < 4; ++mi) {
        const int tt0 = mi * 16 + q * 4;
#pragma unroll
        for (int ni = 0; ni < 4; ++ni) {
            const int n  = n0 + wn + ni * 16 + l15;
            const int bb = n >> 7;
            const int d  = n & 127;
#pragma unroll
            for (int r = 0; r < 4; ++r) {
                const int tt = tt0 + r;
                const int i  = tt * 64 + s;
                float v = acc[mi][ni][r] + gcb[(size_t)i * DH + d];
                v = v > 0.f ? v : 0.f;
                out[(((size_t)bb * NS + s) * NT + tt) * DH + d] = v;
            }
        }
    }
}

// ---- fallback: fused kernel (used only if ws too small) ----
#define APAD 40
#define XPAD 20
__global__ __launch_bounds__(256, 2)
void gcn_fused(const float* __restrict__ hmat, const float* __restrict__ aam,
               const float* __restrict__ gcw, const float* __restrict__ gcb,
               float* __restrict__ out)
{
    __shared__ short sA[TM * APAD];
    __shared__ unsigned int sX[DH * XPAD];
    const int tid = threadIdx.x;
    const int bid = blockIdx.x;
    const int mp  = (bid & 7) * 4 + (bid >> 7);
    const int b   = (bid >> 3) & 15;
    const int i0  = mp * TM;
    const int lane = tid & 63;
    const int wm = ((tid >> 6) >> 1) * 64;
    const int wn = ((tid >> 6) & 1) * 64;
    const int l15 = lane & 15;
    const int q   = lane >> 4;
    floatx4 acc[4][4];
#pragma unroll
    for (int mi = 0; mi < 4; ++mi)
#pragma unroll
        for (int ni = 0; ni < 4; ++ni) acc[mi][ni] = (floatx4){0.f,0.f,0.f,0.f};
    const int ar = tid >> 2, ac = (tid & 3) << 3;
    const int kp = tid >> 4, dg = (tid & 15) << 3;
    const int wkey = (tid & 3) << 2;
    for (int k0 = 0; k0 < KDIM; k0 += 32) {
        const size_t ga0 = (size_t)(i0 + ar) * KDIM + (k0 + ac);
        const size_t ga1 = ga0 + (size_t)64 * KDIM;
        floatx4 aa0a = *(const floatx4*)(aam + ga0), aa0b = *(const floatx4*)(aam + ga0 + 4);
        floatx4 ww0a = *(const floatx4*)(gcw + ga0), ww0b = *(const floatx4*)(gcw + ga0 + 4);
        floatx4 aa1a = *(const floatx4*)(aam + ga1), aa1b = *(const floatx4*)(aam + ga1 + 4);
        floatx4 ww1a = *(const floatx4*)(gcw + ga1), ww1b = *(const floatx4*)(gcw + ga1 + 4);
        const int jj = k0 + 2 * kp, tt = jj >> 6, cc = jj & 63;
        const size_t gx0 = ((size_t)(b * NC + cc) * NT + tt) * DH + dg;
        const size_t gx1 = gx0 + (size_t)NT * DH;
        floatx4 x0a = *(const floatx4*)(hmat + gx0), x0b = *(const floatx4*)(hmat + gx0 + 4);
        floatx4 x1a = *(const floatx4*)(hmat + gx1), x1b = *(const floatx4*)(hmat + gx1 + 4);
        __syncthreads();
        short8 p0, p1;
#pragma unroll
        for (int e = 0; e < 4; ++e) {
            float v0 = aa0a[e]*ww0a[e]; v0 = v0>0.f?v0:0.f;
            float v1 = aa0b[e]*ww0b[e]; v1 = v1>0.f?v1:0.f;
            float v2 = aa1a[e]*ww1a[e]; v2 = v2>0.f?v2:0.f;
            float v3 = aa1b[e]*ww1b[e]; v3 = v3>0.f?v3:0.f;
            p0[e] = (short)f2bf(v0); p0[e+4] = (short)f2bf(v1);
            p1[e] = (short)f2bf(v2); p1[e+4] = (short)f2bf(v3);
        }
        *(short8*)&sA[ar * APAD + ac] = p0;
        *(short8*)&sA[(ar + 64) * APAD + ac] = p1;
#pragma unroll
        for (int e = 0; e < 4; ++e) {
            unsigned int pka = (unsigned int)f2bf(x0a[e]) | ((unsigned int)f2bf(x1a[e]) << 16);
            unsigned int pkb = (unsigned int)f2bf(x0b[e]) | ((unsigned int)f2bf(x1b[e]) << 16);
            sX[(dg + e) * XPAD + (kp ^ wkey)] = pka;
            sX[(dg + e + 4) * XPAD + (kp ^ wkey)] = pkb;
        }
        __syncthreads();
        short8 afrag[4], bfrag[4];
#pragma unroll
        for (int mi = 0; mi < 4; ++mi)
            afrag[mi] = *(const short8*)&sA[(wm + mi * 16 + l15) * APAD + q * 8];
#pragma unroll
        for (int ni = 0; ni < 4; ++ni) {
            const int row = wn + ni * 16 + l15;
            const int col = (q * 4) ^ (((row >> 3) & 3) << 2);
            bfrag[ni] = *(const short8*)(sX + row * XPAD + col);
        }
#pragma unroll
        for (int mi = 0; mi < 4; ++mi)
#pragma unroll
            for (int ni = 0; ni < 4; ++ni)
                acc[mi][ni] = __builtin_amdgcn_mfma_f32_16x16x32_bf16(
                    afrag[mi], bfrag[ni], acc[mi][ni], 0, 0, 0);
    }
#pragma unroll
    for (int mi = 0; mi < 4; ++mi) {
        const int ibase = i0 + wm + mi * 16 + q * 4;
#pragma unroll
        for (int ni = 0; ni < 4; ++ni) {
            const int d = wn + ni * 16 + l15;
#pragma unroll
            for (int r = 0; r < 4; ++r) {
                const int i = ibase + r;
                float v = acc[mi][ni][r] + gcb[(size_t)i * DH + d];
                v = v > 0.f ? v : 0.f;
                out[(((size_t)b * NS + (i & 63)) * NT + (i >> 6)) * DH + d] = v;
            }
        }
    }
}

extern "C" void kernel_launch(void* const* d_in, const int* in_sizes, int n_in,
                              void* d_out, int out_size, void* d_ws, size_t ws_size,
                              hipStream_t stream) {
    const float* h   = (const float*)d_in[0];
    const float* aam = (const float*)d_in[2];
    const float* gcw = (const float*)d_in[3];
    const float* gcb = (const float*)d_in[4];
    float* out = (float*)d_out;

    const size_t A_BYTES   = (size_t)MDIM * KPAD * 2;            // 33.55 MB
    const size_t XT_BYTES  = (size_t)BATCH * DH * KPAD * 2;      // 16.78 MB
    const size_t CP_BYTES  = 32 * 64 * 4;                        // 8 KB
    const size_t NTP_BYTES = 32 * 4;

    if (ws_size >= A_BYTES + XT_BYTES + CP_BYTES + NTP_BYTES) {
        unsigned short* Abf = (unsigned short*)d_ws;
        unsigned short* XTp = (unsigned short*)((char*)d_ws + A_BYTES);
        int* cpair          = (int*)((char*)d_ws + A_BYTES + XT_BYTES);
        int* ntp            = (int*)((char*)d_ws + A_BYTES + XT_BYTES + CP_BYTES);
        prep<<<dim3(2048), 256, 0, stream>>>(aam, gcw, h, Abf, XTp, cpair, ntp);
        gemm<<<dim3(32 * 8), 512, 0, stream>>>(Abf, XTp, cpair, ntp, gcb, out);
    } else {
        gcn_fused<<<dim3((MDIM / TM) * BATCH), 256, 0, stream>>>(h, aam, gcw, gcb, out);
    }
}